// Round 1
// baseline (465.693 us; speedup 1.0000x reference)
//
#include <hip/hip_runtime.h>
#include <hip/hip_bf16.h>

typedef __bf16 bf16_t;
typedef __bf16 bf16x8 __attribute__((ext_vector_type(8)));
typedef __bf16 bf16x4 __attribute__((ext_vector_type(4)));
typedef float  f32x4  __attribute__((ext_vector_type(4)));

#define MFMA16(a,b,c) __builtin_amdgcn_mfma_f32_16x16x32_bf16((a),(b),(c),0,0,0)

static constexpr int Bn = 4, Hn = 16, Dh = 64, SEQ = 1024;

// ---------------------------------------------------------------------------
// Generic tiled GEMM: C[M][N] = A[M][KD] @ W[KD][N] + bias, then epilogue:
//   MODE 0: out bf16 scattered [B][H][S][64]   (k, q projections)
//   MODE 1: out bf16 scattered [B][H][64][S]   (v projection, transposed)
//   MODE 2: out f32 linear [M][N]              (final output GEMM)
// A is f32 (projections) or bf16 (ctx); W is f32, converted on the fly.
// Block: 256 thr = 4 waves (2x2), tile 128x128, BK=32, 16x16x32 bf16 MFMA.
// ---------------------------------------------------------------------------
template<int KD, int N, int MODE, typename AT>
__global__ __launch_bounds__(256)
void gemm_kernel(const AT* __restrict__ A, const float* __restrict__ W,
                 const float* __restrict__ bias, void* __restrict__ outp,
                 float scale)
{
    __shared__ bf16_t As[128][40];   // row-pad 40 (80B) -> 2-way-free banks
    __shared__ bf16_t Bs[128][40];   // stored transposed: [n][k]
    const int t   = threadIdx.x;
    const int lane = t & 63;
    const int w    = t >> 6;
    const int wr = w >> 1, wc = w & 1;
    const int row0 = blockIdx.y * 128;
    const int col0 = blockIdx.x * 128;
    const int lrow = lane & 15;
    const int lk8  = (lane >> 4) * 8;

    f32x4 acc[4][4] = {};

    for (int kk = 0; kk < KD; kk += 32) {
        // ---- stage A tile (128 x 32) ----
        {
            const int r = t >> 1, c = (t & 1) * 16;
            bf16x8 v0, v1;
            if constexpr (sizeof(AT) == 4) {
                const float* src = (const float*)A + (size_t)(row0 + r) * KD + kk + c;
                f32x4 f0 = *(const f32x4*)(src + 0);
                f32x4 f1 = *(const f32x4*)(src + 4);
                f32x4 f2 = *(const f32x4*)(src + 8);
                f32x4 f3 = *(const f32x4*)(src + 12);
                #pragma unroll
                for (int j = 0; j < 4; j++) {
                    v0[j]     = (bf16_t)f0[j];
                    v0[4 + j] = (bf16_t)f1[j];
                    v1[j]     = (bf16_t)f2[j];
                    v1[4 + j] = (bf16_t)f3[j];
                }
            } else {
                const bf16_t* src = (const bf16_t*)A + (size_t)(row0 + r) * KD + kk + c;
                v0 = *(const bf16x8*)(src);
                v1 = *(const bf16x8*)(src + 8);
            }
            *(bf16x8*)&As[r][c]     = v0;
            *(bf16x8*)&As[r][c + 8] = v1;
        }
        // ---- stage B tile (32 x 128), transposing into Bs[n][k] ----
        {
            const int n0 = (t & 31) * 4, k0 = (t >> 5) * 4;
            const float* src = W + (size_t)(kk + k0) * N + col0 + n0;
            f32x4 r0 = *(const f32x4*)(src);
            f32x4 r1 = *(const f32x4*)(src + N);
            f32x4 r2 = *(const f32x4*)(src + 2 * N);
            f32x4 r3 = *(const f32x4*)(src + 3 * N);
            #pragma unroll
            for (int c = 0; c < 4; c++) {
                bf16x4 col;
                col[0] = (bf16_t)r0[c];
                col[1] = (bf16_t)r1[c];
                col[2] = (bf16_t)r2[c];
                col[3] = (bf16_t)r3[c];
                *(bf16x4*)&Bs[n0 + c][k0] = col;
            }
        }
        __syncthreads();
        bf16x8 af[4], bfr[4];
        #pragma unroll
        for (int mf = 0; mf < 4; mf++)
            af[mf] = *(const bf16x8*)&As[wr * 64 + mf * 16 + lrow][lk8];
        #pragma unroll
        for (int nf = 0; nf < 4; nf++)
            bfr[nf] = *(const bf16x8*)&Bs[wc * 64 + nf * 16 + lrow][lk8];
        #pragma unroll
        for (int mf = 0; mf < 4; mf++)
            #pragma unroll
            for (int nf = 0; nf < 4; nf++)
                acc[mf][nf] = MFMA16(af[mf], bfr[nf], acc[mf][nf]);
        __syncthreads();
    }

    // ---- epilogue ----
    #pragma unroll
    for (int mf = 0; mf < 4; mf++) {
        #pragma unroll
        for (int nf = 0; nf < 4; nf++) {
            const int gcol = col0 + wc * 64 + nf * 16 + lrow;
            const float bv = bias[gcol];
            #pragma unroll
            for (int r = 0; r < 4; r++) {
                const int grow = row0 + wr * 64 + mf * 16 + (lane >> 4) * 4 + r;
                const float v = (acc[mf][nf][r] + bv) * scale;
                if constexpr (MODE == 0) {
                    const int b = grow >> 10, s = grow & 1023;
                    const int h = gcol >> 6, d = gcol & 63;
                    ((bf16_t*)outp)[((size_t)(b * Hn + h) * SEQ + s) * Dh + d] = (bf16_t)v;
                } else if constexpr (MODE == 1) {
                    const int b = grow >> 10, s = grow & 1023;
                    const int h = gcol >> 6, d = gcol & 63;
                    ((bf16_t*)outp)[((size_t)(b * Hn + h) * Dh + d) * SEQ + s] = (bf16_t)v;
                } else {
                    ((float*)outp)[(size_t)grow * N + gcol] = v;
                }
            }
        }
    }
}

// ---------------------------------------------------------------------------
// Flash attention. Grid: B*H*16 blocks; block = 256 thr = 4 waves.
// Each wave owns 16 q-rows; K-tiles of 64 keys; K/V read direct from global
// (256 KB per head -> L2-resident). Online softmax in-register; P goes
// through a per-wave XOR-swizzled LDS strip to re-layout for the PV MFMA.
// Writes pre-mask scores (h==0) to top_score.
// ---------------------------------------------------------------------------
__global__ __launch_bounds__(256)
void attn_kernel(const bf16_t* __restrict__ kbuf, const bf16_t* __restrict__ vT,
                 const bf16_t* __restrict__ qbuf, const int* __restrict__ qmask,
                 const int* __restrict__ kmask, bf16_t* __restrict__ ctx,
                 float* __restrict__ topsc)
{
    __shared__ bf16_t Pall[4][16 * 64];
    const int t = threadIdx.x, lane = t & 63, w = t >> 6;
    const int bidx = blockIdx.x;
    const int qt = bidx & 15, bh = bidx >> 4, b = bh >> 4, h = bh & 15;
    const int lrow = lane & 15, lk4 = lane >> 4, lk8 = lk4 * 8;
    const int wrow0 = qt * 64 + w * 16;
    const bf16_t* kb = kbuf + (size_t)bh * SEQ * Dh;
    const bf16_t* vb = vT + (size_t)bh * Dh * SEQ;
    char* Pw = (char*)&Pall[w][0];

    bf16x8 aq0, aq1;
    {
        const bf16_t* qp = qbuf + ((size_t)bh * SEQ + wrow0 + lrow) * Dh + lk8;
        aq0 = *(const bf16x8*)(qp);
        aq1 = *(const bf16x8*)(qp + 32);
    }
    int qmk[4];
    #pragma unroll
    for (int r = 0; r < 4; r++) qmk[r] = qmask[b * SEQ + wrow0 + lk4 * 4 + r];

    float m_run[4], l_run[4];
    #pragma unroll
    for (int r = 0; r < 4; r++) { m_run[r] = -__builtin_inff(); l_run[r] = 0.f; }
    f32x4 o[4] = {};

    for (int kt = 0; kt < 16; kt++) {
        const int key0 = kt * 64;
        // ---- S = q @ k^T (16 x 64 per wave) ----
        f32x4 s[4] = {};
        #pragma unroll
        for (int nf = 0; nf < 4; nf++) {
            const bf16_t* kp = kb + (size_t)(key0 + nf * 16 + lrow) * Dh + lk8;
            bf16x8 kf0 = *(const bf16x8*)(kp);
            bf16x8 kf1 = *(const bf16x8*)(kp + 32);
            s[nf] = MFMA16(aq0, kf0, s[nf]);
            s[nf] = MFMA16(aq1, kf1, s[nf]);
        }
        // ---- pre-mask top_score for head 0 ----
        if (h == 0) {
            #pragma unroll
            for (int nf = 0; nf < 4; nf++)
                #pragma unroll
                for (int r = 0; r < 4; r++)
                    topsc[((size_t)b * SEQ + wrow0 + lk4 * 4 + r) * SEQ +
                          key0 + nf * 16 + lrow] = s[nf][r];
        }
        // ---- masks (-1e18 exactly, matches reference semantics) ----
        int km[4];
        #pragma unroll
        for (int nf = 0; nf < 4; nf++)
            km[nf] = kmask[b * SEQ + key0 + nf * 16 + lrow];
        float p[4][4], mt[4];
        #pragma unroll
        for (int r = 0; r < 4; r++) mt[r] = -__builtin_inff();
        #pragma unroll
        for (int nf = 0; nf < 4; nf++)
            #pragma unroll
            for (int r = 0; r < 4; r++) {
                const float sv = (qmk[r] && km[nf]) ? s[nf][r] : -1e18f;
                p[nf][r] = sv;
                mt[r] = fmaxf(mt[r], sv);
            }
        // ---- online softmax: row reduce over the 16-lane column group ----
        #pragma unroll
        for (int d = 1; d < 16; d <<= 1)
            #pragma unroll
            for (int r = 0; r < 4; r++) mt[r] = fmaxf(mt[r], __shfl_xor(mt[r], d));
        float resc[4], rs[4];
        #pragma unroll
        for (int r = 0; r < 4; r++) {
            const float mn = fmaxf(m_run[r], mt[r]);
            resc[r] = __expf(m_run[r] - mn);   // exp(-inf)=0 on first tile
            m_run[r] = mn;
            rs[r] = 0.f;
        }
        #pragma unroll
        for (int nf = 0; nf < 4; nf++)
            #pragma unroll
            for (int r = 0; r < 4; r++) {
                p[nf][r] = __expf(p[nf][r] - m_run[r]);
                rs[r] += p[nf][r];
            }
        #pragma unroll
        for (int d = 1; d < 16; d <<= 1)
            #pragma unroll
            for (int r = 0; r < 4; r++) rs[r] += __shfl_xor(rs[r], d);
        #pragma unroll
        for (int r = 0; r < 4; r++) l_run[r] = l_run[r] * resc[r] + rs[r];
        #pragma unroll
        for (int nf = 0; nf < 4; nf++)
            #pragma unroll
            for (int r = 0; r < 4; r++) o[nf][r] *= resc[r];
        // ---- P -> bf16 -> swizzled per-wave LDS strip ----
        #pragma unroll
        for (int nf = 0; nf < 4; nf++)
            #pragma unroll
            for (int r = 0; r < 4; r++) {
                const int prow = lk4 * 4 + r;
                const int pcol = nf * 16 + lrow;
                *(bf16_t*)(Pw + prow * 128 + ((pcol * 2) ^ ((prow & 7) << 4))) =
                    (bf16_t)p[nf][r];
            }
        __syncthreads();
        // ---- O += P @ V ----
        bf16x8 pa[2];
        #pragma unroll
        for (int ks = 0; ks < 2; ks++) {
            const int coff = (ks * 32 + lk8) * 2;
            pa[ks] = *(const bf16x8*)(Pw + lrow * 128 + (coff ^ ((lrow & 7) << 4)));
        }
        #pragma unroll
        for (int nf = 0; nf < 4; nf++) {
            const bf16_t* vp = vb + (size_t)(nf * 16 + lrow) * SEQ + key0 + lk8;
            bf16x8 v0 = *(const bf16x8*)(vp);
            bf16x8 v1 = *(const bf16x8*)(vp + 32);
            o[nf] = MFMA16(pa[0], v0, o[nf]);
            o[nf] = MFMA16(pa[1], v1, o[nf]);
        }
        __syncthreads();
    }
    // ---- finalize: ctx[b][q][h*64+d] = O / l ----
    #pragma unroll
    for (int nf = 0; nf < 4; nf++)
        #pragma unroll
        for (int r = 0; r < 4; r++) {
            const int grow = wrow0 + lk4 * 4 + r;
            const float val = o[nf][r] / l_run[r];
            ctx[((size_t)b * SEQ + grow) * (Hn * Dh) + h * Dh + nf * 16 + lrow] =
                (bf16_t)val;
        }
}

// ---------------------------------------------------------------------------
extern "C" void kernel_launch(void* const* d_in, const int* in_sizes, int n_in,
                              void* d_out, int out_size, void* d_ws, size_t ws_size,
                              hipStream_t stream)
{
    const float* key   = (const float*)d_in[0];
    const float* value = (const float*)d_in[1];
    const float* query = (const float*)d_in[2];
    const int*   mask  = (const int*)d_in[3];
    const int*   amask = (const int*)d_in[4];
    const float* Wk = (const float*)d_in[5];
    const float* bk = (const float*)d_in[6];
    const float* Wv = (const float*)d_in[7];
    const float* bv = (const float*)d_in[8];
    const float* Wq = (const float*)d_in[9];
    const float* bq = (const float*)d_in[10];
    const float* Wo = (const float*)d_in[11];
    const float* bo = (const float*)d_in[12];

    const size_t per = (size_t)Bn * Hn * SEQ * Dh;   // 4 M elements
    bf16_t* kbuf = (bf16_t*)d_ws;
    bf16_t* vT   = kbuf + per;
    bf16_t* qbuf = vT + per;
    bf16_t* ctx  = qbuf + per;

    float* outf  = (float*)d_out;
    float* topsc = outf + (size_t)Bn * SEQ * 768;

    // k = key @ Wk + bk          -> [B][H][S][64] bf16
    gemm_kernel<1024, 1024, 0, float><<<dim3(8, 32), 256, 0, stream>>>(key, Wk, bk, kbuf, 1.0f);
    // v = value @ Wv + bv        -> [B][H][64][S] bf16 (transposed)
    gemm_kernel<1024, 1024, 1, float><<<dim3(8, 32), 256, 0, stream>>>(value, Wv, bv, vT, 1.0f);
    // q = (query @ Wq + bq)/8    -> [B][H][S][64] bf16
    gemm_kernel<768, 1024, 0, float><<<dim3(8, 32), 256, 0, stream>>>(query, Wq, bq, qbuf, 0.125f);
    // attention + top_score
    attn_kernel<<<dim3(Bn * Hn * 16), 256, 0, stream>>>(kbuf, vT, qbuf, mask, amask, ctx, topsc);
    // output = ctx @ Wo + bo     -> f32 [4096][768]
    gemm_kernel<1024, 768, 2, bf16_t><<<dim3(6, 32), 256, 0, stream>>>(ctx, Wo, bo, outf, 1.0f);
}

// Round 2
// 349.984 us; speedup vs baseline: 1.3306x; 1.3306x over previous
//
#include <hip/hip_runtime.h>
#include <hip/hip_bf16.h>

typedef __bf16 bf16_t;
typedef __bf16 bf16x8 __attribute__((ext_vector_type(8)));
typedef __bf16 bf16x4 __attribute__((ext_vector_type(4)));
typedef __bf16 bf16x2 __attribute__((ext_vector_type(2)));
typedef float  f32x4  __attribute__((ext_vector_type(4)));

#define MFMA16(a,b,c) __builtin_amdgcn_mfma_f32_16x16x32_bf16((a),(b),(c),0,0,0)

static constexpr int Bn = 4, Hn = 16, Dh = 64, SEQ = 1024;

// ---------------------------------------------------------------------------
// Tiled GEMM: C[M][N] = A[M][KD] @ W[KD][N] + bias, epilogues:
//   MODE 0: out bf16 scattered [B][H][S][64]   (k, q projections)
//   MODE 1: out bf16 scattered [B][H][64][S]   (v projection, transposed)
//   MODE 2: out f32 linear [M][N]              (final output GEMM)
// Tile 128x64, BK=32, 4 waves (2x2, wave tile 64x32), reg double-buffered
// staging so next K-step's global loads overlap current step's MFMAs.
// Grid: dim3(N/64, M/128) = 512 blocks -> 2 blocks/CU.
// ---------------------------------------------------------------------------
template<int KD, int N, int MODE, typename AT>
__global__ __launch_bounds__(256)
void gemm_kernel(const AT* __restrict__ A, const float* __restrict__ W,
                 const float* __restrict__ bias, void* __restrict__ outp,
                 float scale)
{
    constexpr int BM = 128, BN = 64, BK = 32;
    __shared__ bf16_t As[BM][40];   // row-pad 40 -> 2-way-free banks
    __shared__ bf16_t Bs[BN][40];   // stored transposed: [n][k]
    const int t = threadIdx.x;
    const int lane = t & 63;
    const int w = t >> 6;
    const int wr = w >> 1, wc = w & 1;
    const int row0 = blockIdx.y * BM;
    const int col0 = blockIdx.x * BN;
    const int lrow = lane & 15;
    const int lk8  = (lane >> 4) * 8;

    // staging indices: A: 16 elems/thread (1 row), B: 8 f32/thread (2 rows x4)
    const int ar = t >> 1, ac = (t & 1) * 16;
    const int bn0 = (t & 15) * 4, bk0 = (t >> 4) * 2;

    f32x4 acc[4][2] = {};

    f32x4  a_f[4];
    bf16x8 a_h[2];
    f32x4  b_r[2];

    auto loadA = [&](int kk) {
        if constexpr (sizeof(AT) == 4) {
            const float* src = (const float*)A + (size_t)(row0 + ar) * KD + kk + ac;
            a_f[0] = *(const f32x4*)(src + 0);
            a_f[1] = *(const f32x4*)(src + 4);
            a_f[2] = *(const f32x4*)(src + 8);
            a_f[3] = *(const f32x4*)(src + 12);
        } else {
            const bf16_t* src = (const bf16_t*)A + (size_t)(row0 + ar) * KD + kk + ac;
            a_h[0] = *(const bf16x8*)(src);
            a_h[1] = *(const bf16x8*)(src + 8);
        }
    };
    auto loadB = [&](int kk) {
        const float* src = W + (size_t)(kk + bk0) * N + col0 + bn0;
        b_r[0] = *(const f32x4*)(src);
        b_r[1] = *(const f32x4*)(src + N);
    };
    auto storeA = [&]() {
        bf16x8 v0, v1;
        if constexpr (sizeof(AT) == 4) {
            #pragma unroll
            for (int j = 0; j < 4; j++) {
                v0[j]     = (bf16_t)a_f[0][j];
                v0[4 + j] = (bf16_t)a_f[1][j];
                v1[j]     = (bf16_t)a_f[2][j];
                v1[4 + j] = (bf16_t)a_f[3][j];
            }
        } else { v0 = a_h[0]; v1 = a_h[1]; }
        *(bf16x8*)&As[ar][ac]     = v0;
        *(bf16x8*)&As[ar][ac + 8] = v1;
    };
    auto storeB = [&]() {
        #pragma unroll
        for (int c = 0; c < 4; c++) {
            bf16x2 p;
            p[0] = (bf16_t)b_r[0][c];
            p[1] = (bf16_t)b_r[1][c];
            *(bf16x2*)&Bs[bn0 + c][bk0] = p;
        }
    };

    loadA(0); loadB(0);
    for (int kk = 0; kk < KD; kk += BK) {
        storeA(); storeB();
        __syncthreads();
        if (kk + BK < KD) { loadA(kk + BK); loadB(kk + BK); }   // overlaps MFMAs
        bf16x8 af[4], bfr[2];
        #pragma unroll
        for (int mf = 0; mf < 4; mf++)
            af[mf] = *(const bf16x8*)&As[wr * 64 + mf * 16 + lrow][lk8];
        #pragma unroll
        for (int nf = 0; nf < 2; nf++)
            bfr[nf] = *(const bf16x8*)&Bs[wc * 32 + nf * 16 + lrow][lk8];
        #pragma unroll
        for (int mf = 0; mf < 4; mf++)
            #pragma unroll
            for (int nf = 0; nf < 2; nf++)
                acc[mf][nf] = MFMA16(af[mf], bfr[nf], acc[mf][nf]);
        __syncthreads();
    }

    #pragma unroll
    for (int mf = 0; mf < 4; mf++) {
        #pragma unroll
        for (int nf = 0; nf < 2; nf++) {
            const int gcol = col0 + wc * 32 + nf * 16 + lrow;
            const float bv = bias[gcol];
            #pragma unroll
            for (int r = 0; r < 4; r++) {
                const int grow = row0 + wr * 64 + mf * 16 + (lane >> 4) * 4 + r;
                const float v = (acc[mf][nf][r] + bv) * scale;
                if constexpr (MODE == 0) {
                    const int b = grow >> 10, s = grow & 1023;
                    const int h = gcol >> 6, d = gcol & 63;
                    ((bf16_t*)outp)[((size_t)(b * Hn + h) * SEQ + s) * Dh + d] = (bf16_t)v;
                } else if constexpr (MODE == 1) {
                    const int b = grow >> 10, s = grow & 1023;
                    const int h = gcol >> 6, d = gcol & 63;
                    ((bf16_t*)outp)[((size_t)(b * Hn + h) * Dh + d) * SEQ + s] = (bf16_t)v;
                } else {
                    ((float*)outp)[(size_t)grow * N + gcol] = v;
                }
            }
        }
    }
}

// ---------------------------------------------------------------------------
// Flash attention. Grid: B*H*16 blocks; block = 256 thr = 4 waves.
// Each wave owns 16 q-rows; 64-key tiles; K/V direct from global (L2-hot).
// NO barriers (P strip is per-wave). Pipeline: V loads issued at tile top
// (used after softmax); next K-tile fragments prefetched right after QK^T
// (used next iteration). Online softmax in-register via 16-lane shfl_xor.
// ---------------------------------------------------------------------------
__global__ __launch_bounds__(256)
void attn_kernel(const bf16_t* __restrict__ kbuf, const bf16_t* __restrict__ vT,
                 const bf16_t* __restrict__ qbuf, const int* __restrict__ qmask,
                 const int* __restrict__ kmask, bf16_t* __restrict__ ctx,
                 float* __restrict__ topsc)
{
    __shared__ bf16_t Pall[4][16 * 64];
    const int t = threadIdx.x, lane = t & 63, w = t >> 6;
    const int bidx = blockIdx.x;
    const int qt = bidx & 15, bh = bidx >> 4, b = bh >> 4, h = bh & 15;
    const int lrow = lane & 15, lk4 = lane >> 4, lk8 = lk4 * 8;
    const int wrow0 = qt * 64 + w * 16;
    const bf16_t* kb = kbuf + (size_t)bh * SEQ * Dh;
    const bf16_t* vb = vT + (size_t)bh * Dh * SEQ;
    char* Pw = (char*)&Pall[w][0];

    bf16x8 aq0, aq1;
    {
        const bf16_t* qp = qbuf + ((size_t)bh * SEQ + wrow0 + lrow) * Dh + lk8;
        aq0 = *(const bf16x8*)(qp);
        aq1 = *(const bf16x8*)(qp + 32);
    }
    int qmk[4];
    #pragma unroll
    for (int r = 0; r < 4; r++) qmk[r] = qmask[b * SEQ + wrow0 + lk4 * 4 + r];

    float m_run[4], l_run[4];
    #pragma unroll
    for (int r = 0; r < 4; r++) { m_run[r] = -__builtin_inff(); l_run[r] = 0.f; }
    f32x4 o[4] = {};

    // preload K fragments for tile 0
    bf16x8 kc0[4], kc1[4];
    #pragma unroll
    for (int nf = 0; nf < 4; nf++) {
        const bf16_t* kp = kb + (size_t)(nf * 16 + lrow) * Dh + lk8;
        kc0[nf] = *(const bf16x8*)(kp);
        kc1[nf] = *(const bf16x8*)(kp + 32);
    }

    for (int kt = 0; kt < 16; kt++) {
        const int key0 = kt * 64;
        // ---- issue V loads for THIS tile (consumed after softmax) ----
        bf16x8 vf0[4], vf1[4];
        #pragma unroll
        for (int nf = 0; nf < 4; nf++) {
            const bf16_t* vp = vb + (size_t)(nf * 16 + lrow) * SEQ + key0 + lk8;
            vf0[nf] = *(const bf16x8*)(vp);
            vf1[nf] = *(const bf16x8*)(vp + 32);
        }
        // ---- S = q @ k^T with preloaded K fragments ----
        f32x4 s[4] = {};
        #pragma unroll
        for (int nf = 0; nf < 4; nf++) {
            s[nf] = MFMA16(aq0, kc0[nf], s[nf]);
            s[nf] = MFMA16(aq1, kc1[nf], s[nf]);
        }
        // ---- prefetch next K tile (consumed next iteration) ----
        bf16x8 kn0[4], kn1[4];
        if (kt < 15) {
            #pragma unroll
            for (int nf = 0; nf < 4; nf++) {
                const bf16_t* kp = kb + (size_t)(key0 + 64 + nf * 16 + lrow) * Dh + lk8;
                kn0[nf] = *(const bf16x8*)(kp);
                kn1[nf] = *(const bf16x8*)(kp + 32);
            }
        }
        // ---- pre-mask top_score for head 0 ----
        if (h == 0) {
            #pragma unroll
            for (int nf = 0; nf < 4; nf++)
                #pragma unroll
                for (int r = 0; r < 4; r++)
                    topsc[((size_t)b * SEQ + wrow0 + lk4 * 4 + r) * SEQ +
                          key0 + nf * 16 + lrow] = s[nf][r];
        }
        // ---- masks (-1e18, matches reference) ----
        int km[4];
        #pragma unroll
        for (int nf = 0; nf < 4; nf++)
            km[nf] = kmask[b * SEQ + key0 + nf * 16 + lrow];
        float p[4][4], mt[4];
        #pragma unroll
        for (int r = 0; r < 4; r++) mt[r] = -__builtin_inff();
        #pragma unroll
        for (int nf = 0; nf < 4; nf++)
            #pragma unroll
            for (int r = 0; r < 4; r++) {
                const float sv = (qmk[r] && km[nf]) ? s[nf][r] : -1e18f;
                p[nf][r] = sv;
                mt[r] = fmaxf(mt[r], sv);
            }
        // ---- online softmax: reduce across the 16-lane column group ----
        #pragma unroll
        for (int d = 1; d < 16; d <<= 1)
            #pragma unroll
            for (int r = 0; r < 4; r++) mt[r] = fmaxf(mt[r], __shfl_xor(mt[r], d));
        float resc[4], rs[4];
        #pragma unroll
        for (int r = 0; r < 4; r++) {
            const float mn = fmaxf(m_run[r], mt[r]);
            resc[r] = __expf(m_run[r] - mn);
            m_run[r] = mn;
            rs[r] = 0.f;
        }
        #pragma unroll
        for (int nf = 0; nf < 4; nf++)
            #pragma unroll
            for (int r = 0; r < 4; r++) {
                p[nf][r] = __expf(p[nf][r] - m_run[r]);
                rs[r] += p[nf][r];
            }
        #pragma unroll
        for (int d = 1; d < 16; d <<= 1)
            #pragma unroll
            for (int r = 0; r < 4; r++) rs[r] += __shfl_xor(rs[r], d);
        #pragma unroll
        for (int r = 0; r < 4; r++) l_run[r] = l_run[r] * resc[r] + rs[r];
        #pragma unroll
        for (int nf = 0; nf < 4; nf++)
            #pragma unroll
            for (int r = 0; r < 4; r++) o[nf][r] *= resc[r];
        // ---- P -> bf16 -> swizzled per-wave LDS strip (no barrier needed) ----
        #pragma unroll
        for (int nf = 0; nf < 4; nf++)
            #pragma unroll
            for (int r = 0; r < 4; r++) {
                const int prow = lk4 * 4 + r;
                const int pcol = nf * 16 + lrow;
                *(bf16_t*)(Pw + prow * 128 + ((pcol * 2) ^ ((prow & 7) << 4))) =
                    (bf16_t)p[nf][r];
            }
        bf16x8 pa[2];
        #pragma unroll
        for (int ks = 0; ks < 2; ks++) {
            const int coff = (ks * 32 + lk8) * 2;
            pa[ks] = *(const bf16x8*)(Pw + lrow * 128 + (coff ^ ((lrow & 7) << 4)));
        }
        // ---- O += P @ V (V fragments issued at tile top) ----
        #pragma unroll
        for (int nf = 0; nf < 4; nf++) {
            o[nf] = MFMA16(pa[0], vf0[nf], o[nf]);
            o[nf] = MFMA16(pa[1], vf1[nf], o[nf]);
        }
        // rotate prefetched K into current
        #pragma unroll
        for (int nf = 0; nf < 4; nf++) { kc0[nf] = kn0[nf]; kc1[nf] = kn1[nf]; }
    }
    // ---- finalize ----
    #pragma unroll
    for (int nf = 0; nf < 4; nf++)
        #pragma unroll
        for (int r = 0; r < 4; r++) {
            const int grow = wrow0 + lk4 * 4 + r;
            const float val = o[nf][r] / l_run[r];
            ctx[((size_t)b * SEQ + grow) * (Hn * Dh) + h * Dh + nf * 16 + lrow] =
                (bf16_t)val;
        }
}

// ---------------------------------------------------------------------------
extern "C" void kernel_launch(void* const* d_in, const int* in_sizes, int n_in,
                              void* d_out, int out_size, void* d_ws, size_t ws_size,
                              hipStream_t stream)
{
    const float* key   = (const float*)d_in[0];
    const float* value = (const float*)d_in[1];
    const float* query = (const float*)d_in[2];
    const int*   mask  = (const int*)d_in[3];
    const int*   amask = (const int*)d_in[4];
    const float* Wk = (const float*)d_in[5];
    const float* bk = (const float*)d_in[6];
    const float* Wv = (const float*)d_in[7];
    const float* bv = (const float*)d_in[8];
    const float* Wq = (const float*)d_in[9];
    const float* bq = (const float*)d_in[10];
    const float* Wo = (const float*)d_in[11];
    const float* bo = (const float*)d_in[12];

    const size_t per = (size_t)Bn * Hn * SEQ * Dh;
    bf16_t* kbuf = (bf16_t*)d_ws;
    bf16_t* vT   = kbuf + per;
    bf16_t* qbuf = vT + per;
    bf16_t* ctx  = qbuf + per;

    float* outf  = (float*)d_out;
    float* topsc = outf + (size_t)Bn * SEQ * 768;

    gemm_kernel<1024, 1024, 0, float><<<dim3(16, 32), 256, 0, stream>>>(key, Wk, bk, kbuf, 1.0f);
    gemm_kernel<1024, 1024, 1, float><<<dim3(16, 32), 256, 0, stream>>>(value, Wv, bv, vT, 1.0f);
    gemm_kernel<768, 1024, 0, float><<<dim3(16, 32), 256, 0, stream>>>(query, Wq, bq, qbuf, 0.125f);
    attn_kernel<<<dim3(Bn * Hn * 16), 256, 0, stream>>>(kbuf, vT, qbuf, mask, amask, ctx, topsc);
    gemm_kernel<1024, 768, 2, bf16_t><<<dim3(12, 32), 256, 0, stream>>>(ctx, Wo, bo, outf, 1.0f);
}